// Round 13
// baseline (556.262 us; speedup 1.0000x reference)
//
#include <hip/hip_runtime.h>

#define N_NODES 100000
#define N_EDGES 1600000
#define IN_SIZE 512
#define HID_SIZE 256
#define OUT_SIZE 40
#define K_STEPS 10
#define ALPHA 0.1f
#define NP 100096          // padded node count (782*128) for h1t rows

// radix-by-dst build
#define NCH 250            // chunks; 250 * 6400 = 1.6M
#define CH_E 6400          // edges per chunk (int4-aligned)
#define NBUK 391           // buckets of 256 nodes; 391*256 = 100096 >= N
// deg_out partial histograms
#define NRS 8              // src ranges
#define HRS 12544          // 8 * 12544 = 100352 >= N
#define NCS 16             // src chunks; 16 * 100000 = 1.6M
#define CS_E 100000

typedef _Float16 half8 __attribute__((ext_vector_type(8)));
typedef _Float16 half4 __attribute__((ext_vector_type(4)));
typedef float f32x4 __attribute__((ext_vector_type(4)));

struct __align__(8) Entry { int s; int d; };

// async global->LDS, 16B per lane (LDS dest = wave-uniform base + lane*16)
__device__ inline void gld_lds16(const void* g, void* l) {
    __builtin_amdgcn_global_load_lds(
        (const __attribute__((address_space(1))) void*)g,
        (__attribute__((address_space(3))) void*)l,
        16, 0, 0);
}

// ---------------- pass 1: per-chunk bucket histogram of dst ----------------
__global__ __launch_bounds__(512) void hist_pass(const int* __restrict__ dst,
                                                 int* __restrict__ cnt) {
    __shared__ int h[NBUK];
    const int t = threadIdx.x, c = blockIdx.x;
    for (int j = t; j < NBUK; j += 512) h[j] = 0;
    __syncthreads();
    const int4* d4 = (const int4*)(dst + c * CH_E);
    for (int i = t; i < CH_E / 4; i += 512) {
        const int4 v = d4[i];
        atomicAdd(&h[v.x >> 8], 1);
        atomicAdd(&h[v.y >> 8], 1);
        atomicAdd(&h[v.z >> 8], 1);
        atomicAdd(&h[v.w >> 8], 1);
    }
    __syncthreads();
    for (int j = t; j < NBUK; j += 512) cnt[c * NBUK + j] = h[j];
}

// ---------------- pass 2: bucket offsets (single block) ----------------
__global__ __launch_bounds__(512) void bucket_scan(const int* __restrict__ cnt,
                                                   int* __restrict__ off,
                                                   int* __restrict__ boff) {
    __shared__ int tot[512];
    const int b = threadIdx.x;
    int s = 0;
    if (b < NBUK)
        for (int c = 0; c < NCH; ++c) s += cnt[c * NBUK + b];
    tot[b] = s;
    __syncthreads();
    for (int o = 1; o < 512; o <<= 1) {
        const int v = (b >= o) ? tot[b - o] : 0;
        __syncthreads();
        tot[b] += v;
        __syncthreads();
    }
    if (b < NBUK) {
        int run = tot[b] - s;           // exclusive prefix
        boff[b] = run;
        for (int c = 0; c < NCH; ++c) { off[c * NBUK + b] = run; run += cnt[c * NBUK + b]; }
        if (b == NBUK - 1) boff[NBUK] = tot[b];
    }
}

// ---------------- pass 3: scatter edges into bucket-grouped ebuf ----------------
__global__ __launch_bounds__(512) void scatter_pass(const int* __restrict__ src,
                                                    const int* __restrict__ dst,
                                                    const int* __restrict__ off,
                                                    Entry* __restrict__ ebuf) {
    __shared__ int cur[NBUK];
    const int t = threadIdx.x, c = blockIdx.x;
    for (int j = t; j < NBUK; j += 512) cur[j] = off[c * NBUK + j];
    __syncthreads();
    const int4* s4 = (const int4*)(src + c * CH_E);
    const int4* d4 = (const int4*)(dst + c * CH_E);
    for (int i = t; i < CH_E / 4; i += 512) {
        const int4 sv = s4[i];
        const int4 dv = d4[i];
        Entry e;
        int p;
        p = atomicAdd(&cur[dv.x >> 8], 1); e.s = sv.x; e.d = dv.x; ebuf[p] = e;
        p = atomicAdd(&cur[dv.y >> 8], 1); e.s = sv.y; e.d = dv.y; ebuf[p] = e;
        p = atomicAdd(&cur[dv.z >> 8], 1); e.s = sv.z; e.d = dv.z; ebuf[p] = e;
        p = atomicAdd(&cur[dv.w >> 8], 1); e.s = sv.w; e.d = dv.w; ebuf[p] = e;
    }
}

// ---------------- pass 4: per-bucket CSR fill + rowp + ndst ----------------
__global__ __launch_bounds__(256) void bucket_csr(const Entry* __restrict__ ebuf,
                                                  const int* __restrict__ boff,
                                                  int* __restrict__ rowp,
                                                  float* __restrict__ ndst,
                                                  int* __restrict__ csr) {
    __shared__ int hist[256];
    __shared__ int pref[256];
    __shared__ int cur[256];
    const int t = threadIdx.x, b = blockIdx.x;
    const int beg = boff[b], end = boff[b + 1];
    hist[t] = 0;
    __syncthreads();
    for (int i = beg + t; i < end; i += 256)
        atomicAdd(&hist[ebuf[i].d & 255], 1);
    __syncthreads();
    const int h = hist[t];
    pref[t] = h;
    __syncthreads();
    for (int o = 1; o < 256; o <<= 1) {
        const int v = (t >= o) ? pref[t - o] : 0;
        __syncthreads();
        pref[t] += v;
        __syncthreads();
    }
    const int val = beg + pref[t] - h;   // exclusive prefix + bucket base
    const int n = (b << 8) + t;
    if (n <= N_NODES) rowp[n] = val;
    if (n < N_NODES) ndst[n] = 1.0f / sqrtf((float)max(h, 1));
    cur[t] = val;
    __syncthreads();
    for (int i = beg + t; i < end; i += 256) {
        const Entry e = ebuf[i];
        const int pos = atomicAdd(&cur[e.d & 255], 1);
        csr[pos] = e.s;
    }
}

// ---------------- deg_out: range x chunk partial histograms ----------------
__global__ __launch_bounds__(512) void degsrc_part(const int* __restrict__ src,
                                                   int* __restrict__ partial) {
    __shared__ int h[HRS];
    const int t = threadIdx.x;
    const int r = blockIdx.x & (NRS - 1);
    const int c = blockIdx.x >> 3;
    const int base = r * HRS;
    for (int j = t; j < HRS; j += 512) h[j] = 0;
    __syncthreads();
    const int4* s4 = (const int4*)(src + (size_t)c * CS_E);
    for (int i = t; i < CS_E / 4; i += 512) {
        const int4 v = s4[i];
        unsigned u;
        u = (unsigned)(v.x - base); if (u < HRS) atomicAdd(&h[u], 1);
        u = (unsigned)(v.y - base); if (u < HRS) atomicAdd(&h[u], 1);
        u = (unsigned)(v.z - base); if (u < HRS) atomicAdd(&h[u], 1);
        u = (unsigned)(v.w - base); if (u < HRS) atomicAdd(&h[u], 1);
    }
    __syncthreads();
    for (int j = t; j < HRS; j += 512) partial[(size_t)c * (NRS * HRS) + base + j] = h[j];
}

__global__ __launch_bounds__(256) void nsrc_reduce(const int* __restrict__ partial,
                                                   float* __restrict__ nsrc) {
    const int n = blockIdx.x * 256 + threadIdx.x;
    int s = 0;
#pragma unroll
    for (int c = 0; c < NCS; ++c) s += partial[(size_t)c * (NRS * HRS) + n];
    if (n < N_NODES) nsrc[n] = 1.0f / sqrtf((float)max(s, 1));
}

// ---------------- prep: W1 as 8 pre-swizzled per-K-tile LDS images ----------
__global__ __launch_bounds__(256) void prep_w1tp(const float* __restrict__ W1,
                                                 unsigned short* __restrict__ w1tp) {
    int idx = blockIdx.x * 256 + threadIdx.x;
    if (idx < IN_SIZE * HID_SIZE) {
        const int kt  = idx >> 14;         // 0..7
        const int p   = idx & 16383;
        const int n   = p >> 6;            // 0..255
        const int off = p & 63;
        const int j   = off & 7;
        const int ch  = (off >> 3) ^ (n & 7);
        const int kg  = kt * 64 + ch * 8 + j;   // 0..511
        _Float16 h = (_Float16)W1[(size_t)kg * HID_SIZE + n];
        w1tp[idx] = *(unsigned short*)&h;
    }
}

// ---------------- GEMM1: h1t = relu(X @ W1 + b1)^T, fp16 MFMA ----------------
// R12 K-loop (async-B DMA + manual A staging). NEW epilogue: writes h1t[c][n]
// (column-major) with contiguous 8B half4 stores -> dense line population,
// fixes the 2.8x partial-sector writeback amplification of scalar 2B stores.
__global__ __launch_bounds__(512) void gemm1_f16(const float* __restrict__ X,
                                                 const unsigned short* __restrict__ w1tp,
                                                 const float* __restrict__ b1,
                                                 _Float16* __restrict__ h1t) {
    __shared__ __align__(16) _Float16 sA[128 * 64];
    __shared__ __align__(16) _Float16 sB[256 * 64];

    const int t    = threadIdx.x;
    const int lane = t & 63;
    const int w    = t >> 6;
    const int wr   = w >> 2;
    const int wc   = w & 3;
    const int n0   = blockIdx.x * 128;

    f32x4 acc[4][4];
#pragma unroll
    for (int i = 0; i < 4; ++i)
#pragma unroll
        for (int j = 0; j < 4; ++j) acc[i][j] = (f32x4)0.f;

    const int lo = lane & 15;
    const int hi = lane >> 4;
    const int l7 = lane & 7;

    for (int kk = 0; kk < IN_SIZE; kk += 64) {
        __syncthreads();
        // ---- B: async DMA of the pre-swizzled 32KB tile image ----
        {
            const unsigned short* gsrc = w1tp + ((size_t)(kk >> 6) << 14);
#pragma unroll
            for (int i = 0; i < 4; ++i) {
                const int c = t + i * 512;      // 16B chunk id 0..2047
                gld_lds16(gsrc + c * 8, &sB[c * 8]);
            }
        }
        // ---- A: X[128 rows][kk..kk+63] -> fp16, swizzled ----
#pragma unroll
        for (int i = 0; i < 2; ++i) {
            int id  = t + i * 512;
            int row = id >> 3;
            int ch  = id & 7;
            int gr  = n0 + row;
            float4 x0 = make_float4(0.f, 0.f, 0.f, 0.f), x1 = x0;
            if (gr < N_NODES) {
                const float* p = X + (size_t)gr * IN_SIZE + kk + ch * 8;
                x0 = ((const float4*)p)[0];
                x1 = ((const float4*)p)[1];
            }
            half8 hv;
            hv[0] = (_Float16)x0.x; hv[1] = (_Float16)x0.y;
            hv[2] = (_Float16)x0.z; hv[3] = (_Float16)x0.w;
            hv[4] = (_Float16)x1.x; hv[5] = (_Float16)x1.y;
            hv[6] = (_Float16)x1.z; hv[7] = (_Float16)x1.w;
            *(half8*)&sA[row * 64 + ((ch ^ (row & 7)) << 3)] = hv;
        }
        __syncthreads();   // compiler drains vmcnt (DMA) + lgkmcnt here
        // ---- compute: 2 k-slices of 32 ----
#pragma unroll
        for (int s = 0; s < 2; ++s) {
            const int chs = ((s * 4 + hi) ^ l7) << 3;
            half8 af[4], bf[4];
#pragma unroll
            for (int f = 0; f < 4; ++f)
                af[f] = *(const half8*)&sA[(wr * 64 + f * 16 + lo) * 64 + chs];
#pragma unroll
            for (int f = 0; f < 4; ++f)
                bf[f] = *(const half8*)&sB[(wc * 64 + f * 16 + lo) * 64 + chs];
#pragma unroll
            for (int fi = 0; fi < 4; ++fi)
#pragma unroll
                for (int fj = 0; fj < 4; ++fj)
                    acc[fi][fj] = __builtin_amdgcn_mfma_f32_16x16x32_f16(
                        af[fi], bf[fj], acc[fi][fj], 0, 0, 0);
        }
    }

    // ---- epilogue: +b1, relu, transposed contiguous half4 stores ----
    float b1v[4];
#pragma unroll
    for (int fj = 0; fj < 4; ++fj) b1v[fj] = b1[wc * 64 + fj * 16 + lo];
#pragma unroll
    for (int fi = 0; fi < 4; ++fi) {
        const int nb = n0 + wr * 64 + fi * 16 + hi * 4;   // 4 consecutive rows
#pragma unroll
        for (int fj = 0; fj < 4; ++fj) {
            const int c = wc * 64 + fj * 16 + lo;
            half4 hv;
#pragma unroll
            for (int r = 0; r < 4; ++r)
                hv[r] = (_Float16)fmaxf(acc[fi][fj][r] + b1v[fj], 0.f);
            *(half4*)(h1t + (size_t)c * NP + nb) = hv;    // 8B contiguous
        }
    }
}

// ---------------- GEMM2t: h0[n][o] = sum_c h1t[c][n]*W2[c][o] + b2[o] --------
// 256 threads = 256 nodes/block. W2 in LDS (broadcast reads are free);
// h1t reads perfectly coalesced (128B/wave per c); each line read by exactly
// one block -> pure stream. FMA-bound ~13-15us.
__global__ __launch_bounds__(256) void gemm2t(const _Float16* __restrict__ h1t,
                                              const float* __restrict__ W2,
                                              const float* __restrict__ b2,
                                              float* __restrict__ h0) {
    __shared__ float sW2[HID_SIZE * OUT_SIZE];   // [c][o], 40KB
    const int t = threadIdx.x;
    const int n = blockIdx.x * 256 + t;
    for (int i = t; i < HID_SIZE * OUT_SIZE; i += 256) sW2[i] = W2[i];
    __syncthreads();

    float acc[OUT_SIZE];
#pragma unroll
    for (int o = 0; o < OUT_SIZE; ++o) acc[o] = b2[o];

    const _Float16* hp = h1t + n;
#pragma unroll 4
    for (int c = 0; c < HID_SIZE; ++c) {
        const float hv = (float)hp[(size_t)c * NP];
        const float* wrow = &sW2[c * OUT_SIZE];
#pragma unroll
        for (int o = 0; o < OUT_SIZE; ++o)
            acc[o] = fmaf(hv, wrow[o], acc[o]);
    }

    if (n < N_NODES) {
        float* dst = h0 + (size_t)n * OUT_SIZE;
#pragma unroll
        for (int o = 0; o < OUT_SIZE; o += 4)
            *(f32x4*)(dst + o) = *(f32x4*)&acc[o];
    }
}

// ---------------- g0 = nsrc * h0, fp16, rows padded to 64 halves (128B) ------
__global__ __launch_bounds__(320) void g0_init(const float* __restrict__ h0,
                                               const float* __restrict__ nsrc,
                                               _Float16* __restrict__ g) {
    const int tid = threadIdx.x;
    const int ln  = tid / 5;
    const int q   = tid - ln * 5;
    const int n   = blockIdx.x * 64 + ln;
    if (n >= N_NODES) return;
    const float ns = nsrc[n];
    const f32x4 a = *(const f32x4*)(h0 + (size_t)n * OUT_SIZE + q * 8);
    const f32x4 b = *(const f32x4*)(h0 + (size_t)n * OUT_SIZE + q * 8 + 4);
    half8 gv;
    gv[0] = (_Float16)(ns * a[0]); gv[1] = (_Float16)(ns * a[1]);
    gv[2] = (_Float16)(ns * a[2]); gv[3] = (_Float16)(ns * a[3]);
    gv[4] = (_Float16)(ns * b[0]); gv[5] = (_Float16)(ns * b[1]);
    gv[6] = (_Float16)(ns * b[2]); gv[7] = (_Float16)(ns * b[3]);
    *(half8*)(g + (size_t)n * 64 + q * 8) = gv;
}

// ---------------- APPNP step: scaled fp16 state, unweighted gather ----------
__global__ __launch_bounds__(320) void appnp_step3(const _Float16* __restrict__ gin,
                                                   const float* __restrict__ h0,
                                                   const int* __restrict__ rowp,
                                                   const int* __restrict__ csr,
                                                   const float* __restrict__ nsrc,
                                                   const float* __restrict__ ndst,
                                                   _Float16* __restrict__ gout,
                                                   float* __restrict__ hout,
                                                   int last) {
    const int tid = threadIdx.x;
    const int ln  = tid / 5;
    const int q   = tid - ln * 5;
    const int n   = blockIdx.x * 64 + ln;
    if (n >= N_NODES) return;

    const int beg = rowp[n];
    const int end = rowp[n + 1];
    const _Float16* gq = gin + q * 8;

    float acc[8];
#pragma unroll
    for (int j = 0; j < 8; ++j) acc[j] = 0.f;

    int e = beg;
    for (; e + 4 <= end; e += 4) {
        const int s0 = csr[e + 0];
        const int s1 = csr[e + 1];
        const int s2 = csr[e + 2];
        const int s3 = csr[e + 3];
        const half8 v0 = *(const half8*)(gq + (size_t)s0 * 64);
        const half8 v1 = *(const half8*)(gq + (size_t)s1 * 64);
        const half8 v2 = *(const half8*)(gq + (size_t)s2 * 64);
        const half8 v3 = *(const half8*)(gq + (size_t)s3 * 64);
#pragma unroll
        for (int j = 0; j < 8; ++j)
            acc[j] += (float)v0[j] + (float)v1[j] + (float)v2[j] + (float)v3[j];
    }
    for (; e < end; ++e) {
        const int s0 = csr[e];
        const half8 v0 = *(const half8*)(gq + (size_t)s0 * 64);
#pragma unroll
        for (int j = 0; j < 8; ++j) acc[j] += (float)v0[j];
    }

    const float nd = (1.0f - ALPHA) * ndst[n];
    const f32x4 h0a = *(const f32x4*)(h0 + (size_t)n * OUT_SIZE + q * 8);
    const f32x4 h0b = *(const f32x4*)(h0 + (size_t)n * OUT_SIZE + q * 8 + 4);
    float r[8];
    r[0] = nd * acc[0] + ALPHA * h0a[0]; r[1] = nd * acc[1] + ALPHA * h0a[1];
    r[2] = nd * acc[2] + ALPHA * h0a[2]; r[3] = nd * acc[3] + ALPHA * h0a[3];
    r[4] = nd * acc[4] + ALPHA * h0b[0]; r[5] = nd * acc[5] + ALPHA * h0b[1];
    r[6] = nd * acc[6] + ALPHA * h0b[2]; r[7] = nd * acc[7] + ALPHA * h0b[3];

    if (last) {
        f32x4 ra, rb;
        ra[0] = r[0]; ra[1] = r[1]; ra[2] = r[2]; ra[3] = r[3];
        rb[0] = r[4]; rb[1] = r[5]; rb[2] = r[6]; rb[3] = r[7];
        *(f32x4*)(hout + (size_t)n * OUT_SIZE + q * 8) = ra;
        *(f32x4*)(hout + (size_t)n * OUT_SIZE + q * 8 + 4) = rb;
    } else {
        const float ns = nsrc[n];
        half8 gv;
#pragma unroll
        for (int j = 0; j < 8; ++j) gv[j] = (_Float16)(ns * r[j]);
        *(half8*)(gout + (size_t)n * 64 + q * 8) = gv;
    }
}

// ---------------- launcher (R6 ordering: MLP first, build second) ------------
extern "C" void kernel_launch(void* const* d_in, const int* in_sizes, int n_in,
                              void* d_out, int out_size, void* d_ws, size_t ws_size,
                              hipStream_t stream) {
    const float* X   = (const float*)d_in[0];
    const int*   src = (const int*)d_in[1];
    const int*   dst = (const int*)d_in[2];
    const float* W1  = (const float*)d_in[3];
    const float* b1  = (const float*)d_in[4];
    const float* W2  = (const float*)d_in[5];
    const float* b2  = (const float*)d_in[6];
    float* out = (float*)d_out;

    char* ws = (char*)d_ws;
    size_t off = 0;
    auto alloc = [&](size_t bytes) -> void* {
        void* p = ws + off;
        off = (off + bytes + 255) & ~(size_t)255;
        return p;
    };
    // persistent
    float* h0 = (float*)alloc((size_t)N_NODES * OUT_SIZE * 4);     // 16 MB
    const size_t mark = off;

    // ---- phase A (MLP) region ----
    unsigned short* w1tp = (unsigned short*)alloc((size_t)IN_SIZE * HID_SIZE * 2); // 256 KB
    _Float16*       h1t  = (_Float16*)alloc((size_t)HID_SIZE * NP * 2);            // 51.2 MB

    // ---- phase B region: aliases phase A (w1tp/h1t dead after gemm2t) ----
    off = mark;
    _Float16* gA = (_Float16*)alloc((size_t)N_NODES * 64 * 2);   // 12.8 MB
    _Float16* gB = (_Float16*)alloc((size_t)N_NODES * 64 * 2);   // 12.8 MB
    // partial (6.5 MB) aliases gA: dead before g0_init writes gA
    int*   partial = (int*)gA;                                   // [NCS][NRS*HRS]
    // ebuf (12.8 MB) aliases gB: dead before step 0 writes gB
    Entry* ebuf    = (Entry*)gB;
    float* nsrc = (float*)alloc((size_t)N_NODES * 4);
    float* ndst = (float*)alloc((size_t)N_NODES * 4);
    int* rowp   = (int*)alloc((size_t)(N_NODES + 2) * 4);
    int* csr    = (int*)alloc((size_t)N_EDGES * 4);              // 6.4 MB
    int* cnt    = (int*)alloc((size_t)NCH * NBUK * 4);           // 391 KB
    int* offb   = (int*)alloc((size_t)NCH * NBUK * 4);           // 391 KB
    int* boff   = (int*)alloc((size_t)(NBUK + 1) * 4);

    const int pgrid = (N_NODES + 63) / 64;             // 1563 (320-thread blocks)
    const int ngrid256 = (N_NODES + 255) / 256;        // 391

    // ---- phase A: MLP ----
    prep_w1tp<<<(IN_SIZE * HID_SIZE + 255) / 256, 256, 0, stream>>>(W1, w1tp);
    gemm1_f16<<<(N_NODES + 127) / 128, 512, 0, stream>>>(X, w1tp, b1, h1t);
    gemm2t<<<ngrid256, 256, 0, stream>>>(h1t, W2, b2, h0);

    // ---- phase B: radix CSR build (no device atomics anywhere) ----
    hist_pass<<<NCH, 512, 0, stream>>>(dst, cnt);
    bucket_scan<<<1, 512, 0, stream>>>(cnt, offb, boff);
    scatter_pass<<<NCH, 512, 0, stream>>>(src, dst, offb, ebuf);
    bucket_csr<<<NBUK, 256, 0, stream>>>(ebuf, boff, rowp, ndst, csr);

    // ---- deg_out -> nsrc (non-atomic partial histograms) ----
    degsrc_part<<<NRS * NCS, 512, 0, stream>>>(src, partial);
    nsrc_reduce<<<(NRS * HRS) / 256, 256, 0, stream>>>(partial, nsrc);

    // ---- scaled initial state (partial dead; gA now live) ----
    g0_init<<<pgrid, 320, 0, stream>>>(h0, nsrc, gA);

    // ---- propagation (ebuf dead; gB now live) ----
    const _Float16* gin = gA;
    for (int s = 0; s < K_STEPS; ++s) {
        const int last = (s == K_STEPS - 1) ? 1 : 0;
        _Float16* gout = (s & 1) ? gA : gB;
        appnp_step3<<<pgrid, 320, 0, stream>>>(gin, h0, rowp, csr, nsrc, ndst,
                                               gout, out, last);
        gin = gout;
    }
}

// Round 14
// 478.326 us; speedup vs baseline: 1.1629x; 1.1629x over previous
//
#include <hip/hip_runtime.h>

#define N_NODES 100000
#define N_EDGES 1600000
#define IN_SIZE 512
#define HID_SIZE 256
#define OUT_SIZE 40
#define K_STEPS 10
#define ALPHA 0.1f

// radix-by-dst build
#define NCH 250            // chunks; 250 * 6400 = 1.6M
#define CH_E 6400          // edges per chunk (int4-aligned)
#define NBUK 391           // buckets of 256 nodes; 391*256 = 100096 >= N
// deg_out partial histograms
#define NRS 8              // src ranges
#define HRS 12544          // 8 * 12544 = 100352 >= N
#define NCS 16             // src chunks; 16 * 100000 = 1.6M
#define CS_E 100000

typedef _Float16 half8 __attribute__((ext_vector_type(8)));
typedef float f32x4 __attribute__((ext_vector_type(4)));
typedef float f32x2 __attribute__((ext_vector_type(2)));

struct __align__(8) Entry { int s; int d; };

// async global->LDS, 16B per lane (LDS dest = wave-uniform base + lane*16)
__device__ inline void gld_lds16(const void* g, void* l) {
    __builtin_amdgcn_global_load_lds(
        (const __attribute__((address_space(1))) void*)g,
        (__attribute__((address_space(3))) void*)l,
        16, 0, 0);
}

// ---------------- pass 1: per-chunk bucket histogram of dst ----------------
__global__ __launch_bounds__(512) void hist_pass(const int* __restrict__ dst,
                                                 int* __restrict__ cnt) {
    __shared__ int h[NBUK];
    const int t = threadIdx.x, c = blockIdx.x;
    for (int j = t; j < NBUK; j += 512) h[j] = 0;
    __syncthreads();
    const int4* d4 = (const int4*)(dst + c * CH_E);
    for (int i = t; i < CH_E / 4; i += 512) {
        const int4 v = d4[i];
        atomicAdd(&h[v.x >> 8], 1);
        atomicAdd(&h[v.y >> 8], 1);
        atomicAdd(&h[v.z >> 8], 1);
        atomicAdd(&h[v.w >> 8], 1);
    }
    __syncthreads();
    for (int j = t; j < NBUK; j += 512) cnt[c * NBUK + j] = h[j];
}

// ---------------- pass 2: bucket offsets (single block) ----------------
__global__ __launch_bounds__(512) void bucket_scan(const int* __restrict__ cnt,
                                                   int* __restrict__ off,
                                                   int* __restrict__ boff) {
    __shared__ int tot[512];
    const int b = threadIdx.x;
    int s = 0;
    if (b < NBUK)
        for (int c = 0; c < NCH; ++c) s += cnt[c * NBUK + b];
    tot[b] = s;
    __syncthreads();
    for (int o = 1; o < 512; o <<= 1) {
        const int v = (b >= o) ? tot[b - o] : 0;
        __syncthreads();
        tot[b] += v;
        __syncthreads();
    }
    if (b < NBUK) {
        int run = tot[b] - s;           // exclusive prefix
        boff[b] = run;
        for (int c = 0; c < NCH; ++c) { off[c * NBUK + b] = run; run += cnt[c * NBUK + b]; }
        if (b == NBUK - 1) boff[NBUK] = tot[b];
    }
}

// ---------------- pass 3: scatter edges into bucket-grouped ebuf ----------------
__global__ __launch_bounds__(512) void scatter_pass(const int* __restrict__ src,
                                                    const int* __restrict__ dst,
                                                    const int* __restrict__ off,
                                                    Entry* __restrict__ ebuf) {
    __shared__ int cur[NBUK];
    const int t = threadIdx.x, c = blockIdx.x;
    for (int j = t; j < NBUK; j += 512) cur[j] = off[c * NBUK + j];
    __syncthreads();
    const int4* s4 = (const int4*)(src + c * CH_E);
    const int4* d4 = (const int4*)(dst + c * CH_E);
    for (int i = t; i < CH_E / 4; i += 512) {
        const int4 sv = s4[i];
        const int4 dv = d4[i];
        Entry e;
        int p;
        p = atomicAdd(&cur[dv.x >> 8], 1); e.s = sv.x; e.d = dv.x; ebuf[p] = e;
        p = atomicAdd(&cur[dv.y >> 8], 1); e.s = sv.y; e.d = dv.y; ebuf[p] = e;
        p = atomicAdd(&cur[dv.z >> 8], 1); e.s = sv.z; e.d = dv.z; ebuf[p] = e;
        p = atomicAdd(&cur[dv.w >> 8], 1); e.s = sv.w; e.d = dv.w; ebuf[p] = e;
    }
}

// ---------------- pass 4: per-bucket CSR fill + rowp + ndst ----------------
__global__ __launch_bounds__(256) void bucket_csr(const Entry* __restrict__ ebuf,
                                                  const int* __restrict__ boff,
                                                  int* __restrict__ rowp,
                                                  float* __restrict__ ndst,
                                                  int* __restrict__ csr) {
    __shared__ int hist[256];
    __shared__ int pref[256];
    __shared__ int cur[256];
    const int t = threadIdx.x, b = blockIdx.x;
    const int beg = boff[b], end = boff[b + 1];
    hist[t] = 0;
    __syncthreads();
    for (int i = beg + t; i < end; i += 256)
        atomicAdd(&hist[ebuf[i].d & 255], 1);
    __syncthreads();
    const int h = hist[t];
    pref[t] = h;
    __syncthreads();
    for (int o = 1; o < 256; o <<= 1) {
        const int v = (t >= o) ? pref[t - o] : 0;
        __syncthreads();
        pref[t] += v;
        __syncthreads();
    }
    const int val = beg + pref[t] - h;   // exclusive prefix + bucket base
    const int n = (b << 8) + t;
    if (n <= N_NODES) rowp[n] = val;
    if (n < N_NODES) ndst[n] = 1.0f / sqrtf((float)max(h, 1));
    cur[t] = val;
    __syncthreads();
    for (int i = beg + t; i < end; i += 256) {
        const Entry e = ebuf[i];
        const int pos = atomicAdd(&cur[e.d & 255], 1);
        csr[pos] = e.s;
    }
}

// ---------------- deg_out: range x chunk partial histograms ----------------
__global__ __launch_bounds__(512) void degsrc_part(const int* __restrict__ src,
                                                   int* __restrict__ partial) {
    __shared__ int h[HRS];
    const int t = threadIdx.x;
    const int r = blockIdx.x & (NRS - 1);
    const int c = blockIdx.x >> 3;
    const int base = r * HRS;
    for (int j = t; j < HRS; j += 512) h[j] = 0;
    __syncthreads();
    const int4* s4 = (const int4*)(src + (size_t)c * CS_E);
    for (int i = t; i < CS_E / 4; i += 512) {
        const int4 v = s4[i];
        unsigned u;
        u = (unsigned)(v.x - base); if (u < HRS) atomicAdd(&h[u], 1);
        u = (unsigned)(v.y - base); if (u < HRS) atomicAdd(&h[u], 1);
        u = (unsigned)(v.z - base); if (u < HRS) atomicAdd(&h[u], 1);
        u = (unsigned)(v.w - base); if (u < HRS) atomicAdd(&h[u], 1);
    }
    __syncthreads();
    for (int j = t; j < HRS; j += 512) partial[(size_t)c * (NRS * HRS) + base + j] = h[j];
}

__global__ __launch_bounds__(256) void nsrc_reduce(const int* __restrict__ partial,
                                                   float* __restrict__ nsrc) {
    const int n = blockIdx.x * 256 + threadIdx.x;
    int s = 0;
#pragma unroll
    for (int c = 0; c < NCS; ++c) s += partial[(size_t)c * (NRS * HRS) + n];
    if (n < N_NODES) nsrc[n] = 1.0f / sqrtf((float)max(s, 1));
}

// ---------------- prep: W1 pre-swizzled K-tile images + W2^T fp16 -----------
// w1tp: 8 tiles of [256n][64k] swizzled (linear 32KB copy == sB image).
// w2t:  [48 o][256 c] fp16, rows o>=40 zero-padded.
__global__ __launch_bounds__(256) void prep_w(const float* __restrict__ W1,
                                              const float* __restrict__ W2,
                                              unsigned short* __restrict__ w1tp,
                                              unsigned short* __restrict__ w2t) {
    int idx = blockIdx.x * 256 + threadIdx.x;
    if (idx < IN_SIZE * HID_SIZE) {
        const int kt  = idx >> 14;         // 0..7
        const int p   = idx & 16383;
        const int n   = p >> 6;            // 0..255
        const int off = p & 63;
        const int j   = off & 7;
        const int ch  = (off >> 3) ^ (n & 7);
        const int kg  = kt * 64 + ch * 8 + j;   // 0..511
        _Float16 h = (_Float16)W1[(size_t)kg * HID_SIZE + n];
        w1tp[idx] = *(unsigned short*)&h;
    } else if (idx < IN_SIZE * HID_SIZE + 48 * HID_SIZE) {
        const int i2 = idx - IN_SIZE * HID_SIZE;
        const int o  = i2 >> 8;            // 0..47
        const int c  = i2 & 255;           // 0..255
        const float v = (o < OUT_SIZE) ? W2[(size_t)c * OUT_SIZE + o] : 0.f;
        _Float16 h = (_Float16)v;
        w2t[i2] = *(unsigned short*)&h;
    }
}

// ---------------- fused MLP: h0 = relu(X@W1+b1)@W2+b2 ; g0 = nsrc*h0 --------
// Phase 1: R12's verified staging (manual-A sync + async-DMA-B). NO prefetch
// (R11 isolated reg-prefetch at +70us — it was R7's poison, not the fusion).
// Phase 2: R7's verified 4-round h1-through-LDS MFMA vs fp16 W2^T.
// Epilogue: 128x40 f32 out-tile staged in LDS -> LINEAR coalesced stores.
__global__ __launch_bounds__(512) void gemm_fused(const float* __restrict__ X,
                                                  const unsigned short* __restrict__ w1tp,
                                                  const float* __restrict__ b1,
                                                  const unsigned short* __restrict__ w2t,
                                                  const float* __restrict__ b2,
                                                  const float* __restrict__ nsrc,
                                                  float* __restrict__ h0,
                                                  _Float16* __restrict__ g0) {
    __shared__ __align__(16) unsigned char lds[49152];
    _Float16* sA = (_Float16*)lds;            // [128][64]   phase 1
    _Float16* sB = sA + 128 * 64;             // [256][64]   phase 1
    _Float16* sC = (_Float16*)lds;            // [128][72]   phase 2
    _Float16* sW = sC + 128 * 72;             // [48][264]   phase 2

    const int t    = threadIdx.x;
    const int lane = t & 63;
    const int w    = t >> 6;        // 0..7
    const int wr   = w >> 2;        // 0..1
    const int wc   = w & 3;         // 0..3
    const int n0   = blockIdx.x * 128;

    f32x4 acc[4][4];
#pragma unroll
    for (int i = 0; i < 4; ++i)
#pragma unroll
        for (int j = 0; j < 4; ++j) acc[i][j] = (f32x4)0.f;

    const int lo = lane & 15;
    const int hi = lane >> 4;
    const int l7 = lane & 7;

    for (int kk = 0; kk < IN_SIZE; kk += 64) {
        __syncthreads();
        // ---- B: async DMA of the pre-swizzled 32KB tile image ----
        {
            const unsigned short* gsrc = w1tp + ((size_t)(kk >> 6) << 14);
#pragma unroll
            for (int i = 0; i < 4; ++i) {
                const int c = t + i * 512;      // 16B chunk id 0..2047
                gld_lds16(gsrc + c * 8, &sB[c * 8]);
            }
        }
        // ---- A: X[128 rows][kk..kk+63] -> fp16, swizzled (sync, as R6) ----
#pragma unroll
        for (int i = 0; i < 2; ++i) {
            int id  = t + i * 512;
            int row = id >> 3;
            int ch  = id & 7;
            int gr  = n0 + row;
            float4 x0 = make_float4(0.f, 0.f, 0.f, 0.f), x1 = x0;
            if (gr < N_NODES) {
                const float* p = X + (size_t)gr * IN_SIZE + kk + ch * 8;
                x0 = ((const float4*)p)[0];
                x1 = ((const float4*)p)[1];
            }
            half8 hv;
            hv[0] = (_Float16)x0.x; hv[1] = (_Float16)x0.y;
            hv[2] = (_Float16)x0.z; hv[3] = (_Float16)x0.w;
            hv[4] = (_Float16)x1.x; hv[5] = (_Float16)x1.y;
            hv[6] = (_Float16)x1.z; hv[7] = (_Float16)x1.w;
            *(half8*)&sA[row * 64 + ((ch ^ (row & 7)) << 3)] = hv;
        }
        __syncthreads();   // drains DMA (vmcnt) + LDS writes
        // ---- compute: 2 k-slices of 32 ----
#pragma unroll
        for (int s = 0; s < 2; ++s) {
            const int chs = ((s * 4 + hi) ^ l7) << 3;
            half8 af[4], bf[4];
#pragma unroll
            for (int f = 0; f < 4; ++f)
                af[f] = *(const half8*)&sA[(wr * 64 + f * 16 + lo) * 64 + chs];
#pragma unroll
            for (int f = 0; f < 4; ++f)
                bf[f] = *(const half8*)&sB[(wc * 64 + f * 16 + lo) * 64 + chs];
#pragma unroll
            for (int fi = 0; fi < 4; ++fi)
#pragma unroll
                for (int fj = 0; fj < 4; ++fj)
                    acc[fi][fj] = __builtin_amdgcn_mfma_f32_16x16x32_f16(
                        af[fi], bf[fj], acc[fi][fj], 0, 0, 0);
        }
    }

    // ---------------- phase 2: (relu(h1)) @ W2  (R7-verified) ----------------
    float b1v[4];
#pragma unroll
    for (int fj = 0; fj < 4; ++fj) b1v[fj] = b1[wc * 64 + fj * 16 + lo];

    __syncthreads();   // phase-1 LDS reads done everywhere
#pragma unroll
    for (int i = 0; i < 3; ++i) {
        const int id = t + i * 512;      // 0..1535
        const int o  = id >> 5;          // 0..47
        const int ch = id & 31;
        const uint4 v = *(const uint4*)(w2t + (size_t)o * HID_SIZE + ch * 8);
        *(uint4*)&sW[o * 264 + ch * 8] = v;
    }

    f32x4 acc2[3];
#pragma unroll
    for (int f = 0; f < 3; ++f) acc2[f] = (f32x4)0.f;
    float b2v[3];
#pragma unroll
    for (int f = 0; f < 3; ++f) {
        const int o = f * 16 + lo;
        b2v[f] = (o < OUT_SIZE) ? b2[o] : 0.f;
    }

    for (int j = 0; j < 4; ++j) {
        if (j) __syncthreads();
        if (wc == j) {
#pragma unroll
            for (int fi = 0; fi < 4; ++fi)
#pragma unroll
                for (int fj = 0; fj < 4; ++fj)
#pragma unroll
                    for (int r = 0; r < 4; ++r) {
                        const int rl = wr * 64 + fi * 16 + hi * 4 + r;
                        const int cl = fj * 16 + lo;
                        const float v = fmaxf(acc[fi][fj][r] + b1v[fj], 0.f);
                        sC[rl * 72 + cl] = (_Float16)v;
                    }
        }
        __syncthreads();
#pragma unroll
        for (int ks = 0; ks < 2; ++ks) {
            const half8 a = *(const half8*)&sC[(w * 16 + lo) * 72 + ks * 32 + hi * 8];
#pragma unroll
            for (int f = 0; f < 3; ++f) {
                const half8 b = *(const half8*)&sW[(f * 16 + lo) * 264 + j * 64 + ks * 32 + hi * 8];
                acc2[f] = __builtin_amdgcn_mfma_f32_16x16x32_f16(a, b, acc2[f], 0, 0, 0);
            }
        }
    }

    // ---- epilogue: stage 128x40 f32 tile, then LINEAR coalesced stores ----
    __syncthreads();                      // all MFMA reads of sC/sW done
    float* sOut = (float*)lds;            // [128][40] f32 = 20 KB
#pragma unroll
    for (int f = 0; f < 3; ++f) {
        const int o = f * 16 + lo;
#pragma unroll
        for (int r = 0; r < 4; ++r) {
            const int row = w * 16 + hi * 4 + r;
            if (o < OUT_SIZE) sOut[row * OUT_SIZE + o] = acc2[f][r] + b2v[f];
        }
    }
    __syncthreads();

    const int nvalid = min(128, N_NODES - n0);
    // h0: 128*40 floats = 2560 f32x2, linear
    {
        const int fcount = nvalid * OUT_SIZE;
#pragma unroll
        for (int i = 0; i < 5; ++i) {
            const int idx = t + i * 512;          // f32x2 id, 0..2559
            if (idx * 2 < fcount) {
                f32x2 v;
                v[0] = sOut[idx * 2];
                v[1] = sOut[idx * 2 + 1];
                *(f32x2*)(h0 + (size_t)n0 * OUT_SIZE + idx * 2) = v;
            }
        }
    }
    // g0: 128 rows x 64 halves = 1024 half8, linear (cols >=40 zero)
#pragma unroll
    for (int i = 0; i < 2; ++i) {
        const int idx = t + i * 512;              // half8 id, 0..1023
        const int row = idx >> 3;
        const int q   = idx & 7;
        if (row < nvalid) {
            const int n = n0 + row;
            const float ns = nsrc[n];
            half8 gv;
#pragma unroll
            for (int k = 0; k < 8; ++k) {
                const int col = q * 8 + k;
                const float v = (col < OUT_SIZE) ? ns * sOut[row * OUT_SIZE + col] : 0.f;
                gv[k] = (_Float16)v;
            }
            *(half8*)(g0 + (size_t)n * 64 + q * 8) = gv;
        }
    }
}

// ---------------- APPNP step: scaled fp16 state, unweighted gather ----------
// (R6's step3 — measured best: ~36 us/step)
__global__ __launch_bounds__(320) void appnp_step3(const _Float16* __restrict__ gin,
                                                   const float* __restrict__ h0,
                                                   const int* __restrict__ rowp,
                                                   const int* __restrict__ csr,
                                                   const float* __restrict__ nsrc,
                                                   const float* __restrict__ ndst,
                                                   _Float16* __restrict__ gout,
                                                   float* __restrict__ hout,
                                                   int last) {
    const int tid = threadIdx.x;
    const int ln  = tid / 5;
    const int q   = tid - ln * 5;
    const int n   = blockIdx.x * 64 + ln;
    if (n >= N_NODES) return;

    const int beg = rowp[n];
    const int end = rowp[n + 1];
    const _Float16* gq = gin + q * 8;

    float acc[8];
#pragma unroll
    for (int j = 0; j < 8; ++j) acc[j] = 0.f;

    int e = beg;
    for (; e + 4 <= end; e += 4) {
        const int s0 = csr[e + 0];
        const int s1 = csr[e + 1];
        const int s2 = csr[e + 2];
        const int s3 = csr[e + 3];
        const half8 v0 = *(const half8*)(gq + (size_t)s0 * 64);
        const half8 v1 = *(const half8*)(gq + (size_t)s1 * 64);
        const half8 v2 = *(const half8*)(gq + (size_t)s2 * 64);
        const half8 v3 = *(const half8*)(gq + (size_t)s3 * 64);
#pragma unroll
        for (int j = 0; j < 8; ++j)
            acc[j] += (float)v0[j] + (float)v1[j] + (float)v2[j] + (float)v3[j];
    }
    for (; e < end; ++e) {
        const int s0 = csr[e];
        const half8 v0 = *(const half8*)(gq + (size_t)s0 * 64);
#pragma unroll
        for (int j = 0; j < 8; ++j) acc[j] += (float)v0[j];
    }

    const float nd = (1.0f - ALPHA) * ndst[n];
    const f32x4 h0a = *(const f32x4*)(h0 + (size_t)n * OUT_SIZE + q * 8);
    const f32x4 h0b = *(const f32x4*)(h0 + (size_t)n * OUT_SIZE + q * 8 + 4);
    float r[8];
    r[0] = nd * acc[0] + ALPHA * h0a[0]; r[1] = nd * acc[1] + ALPHA * h0a[1];
    r[2] = nd * acc[2] + ALPHA * h0a[2]; r[3] = nd * acc[3] + ALPHA * h0a[3];
    r[4] = nd * acc[4] + ALPHA * h0b[0]; r[5] = nd * acc[5] + ALPHA * h0b[1];
    r[6] = nd * acc[6] + ALPHA * h0b[2]; r[7] = nd * acc[7] + ALPHA * h0b[3];

    if (last) {
        f32x4 ra, rb;
        ra[0] = r[0]; ra[1] = r[1]; ra[2] = r[2]; ra[3] = r[3];
        rb[0] = r[4]; rb[1] = r[5]; rb[2] = r[6]; rb[3] = r[7];
        *(f32x4*)(hout + (size_t)n * OUT_SIZE + q * 8) = ra;
        *(f32x4*)(hout + (size_t)n * OUT_SIZE + q * 8 + 4) = rb;
    } else {
        const float ns = nsrc[n];
        half8 gv;
#pragma unroll
        for (int j = 0; j < 8; ++j) gv[j] = (_Float16)(ns * r[j]);
        *(half8*)(gout + (size_t)n * 64 + q * 8) = gv;
    }
}

// ---------------- launcher (build first: nsrc feeds the fused epilogue) -----
extern "C" void kernel_launch(void* const* d_in, const int* in_sizes, int n_in,
                              void* d_out, int out_size, void* d_ws, size_t ws_size,
                              hipStream_t stream) {
    const float* X   = (const float*)d_in[0];
    const int*   src = (const int*)d_in[1];
    const int*   dst = (const int*)d_in[2];
    const float* W1  = (const float*)d_in[3];
    const float* b1  = (const float*)d_in[4];
    const float* W2  = (const float*)d_in[5];
    const float* b2  = (const float*)d_in[6];
    float* out = (float*)d_out;

    char* ws = (char*)d_ws;
    size_t off = 0;
    auto alloc = [&](size_t bytes) -> void* {
        void* p = ws + off;
        off = (off + bytes + 255) & ~(size_t)255;
        return p;
    };
    // all disjoint (~70 MB total; no aliasing hazards)
    float*    h0 = (float*)alloc((size_t)N_NODES * OUT_SIZE * 4);   // 16 MB
    _Float16* gA = (_Float16*)alloc((size_t)N_NODES * 64 * 2);      // 12.8 MB
    _Float16* gB = (_Float16*)alloc((size_t)N_NODES * 64 * 2);      // 12.8 MB
    Entry* ebuf    = (Entry*)alloc((size_t)N_EDGES * 8);            // 12.8 MB
    int*   partial = (int*)alloc((size_t)NCS * NRS * HRS * 4);      // 6.5 MB
    float* nsrc = (float*)alloc((size_t)N_NODES * 4);
    float* ndst = (float*)alloc((size_t)N_NODES * 4);
    int* rowp   = (int*)alloc((size_t)(N_NODES + 2) * 4);
    int* csr    = (int*)alloc((size_t)N_EDGES * 4);                 // 6.4 MB
    int* cnt    = (int*)alloc((size_t)NCH * NBUK * 4);
    int* offb   = (int*)alloc((size_t)NCH * NBUK * 4);
    int* boff   = (int*)alloc((size_t)(NBUK + 1) * 4);
    unsigned short* w1tp = (unsigned short*)alloc((size_t)IN_SIZE * HID_SIZE * 2);
    unsigned short* w2t  = (unsigned short*)alloc((size_t)48 * HID_SIZE * 2);

    const int pgrid = (N_NODES + 63) / 64;             // 1563 (320-thread blocks)

    // ---- radix CSR build + norms ----
    hist_pass<<<NCH, 512, 0, stream>>>(dst, cnt);
    bucket_scan<<<1, 512, 0, stream>>>(cnt, offb, boff);
    scatter_pass<<<NCH, 512, 0, stream>>>(src, dst, offb, ebuf);
    bucket_csr<<<NBUK, 256, 0, stream>>>(ebuf, boff, rowp, ndst, csr);
    degsrc_part<<<NRS * NCS, 512, 0, stream>>>(src, partial);
    nsrc_reduce<<<(NRS * HRS) / 256, 256, 0, stream>>>(partial, nsrc);

    // ---- fused MLP: writes h0 + g0 directly ----
    const int wtotal = IN_SIZE * HID_SIZE + 48 * HID_SIZE;          // 143360
    prep_w<<<(wtotal + 255) / 256, 256, 0, stream>>>(W1, W2, w1tp, w2t);
    gemm_fused<<<(N_NODES + 127) / 128, 512, 0, stream>>>(X, w1tp, b1, w2t, b2,
                                                          nsrc, h0, gA);

    // ---- propagation ----
    const _Float16* gin = gA;
    for (int s = 0; s < K_STEPS; ++s) {
        const int last = (s == K_STEPS - 1) ? 1 : 0;
        _Float16* gout = (s & 1) ? gA : gB;
        appnp_step3<<<pgrid, 320, 0, stream>>>(gin, h0, rowp, csr, nsrc, ndst,
                                               gout, out, last);
        gin = gout;
    }
}